// Round 9
// baseline (163.208 us; speedup 1.0000x reference)
//
#include <hip/hip_runtime.h>
#include <cmath>

#define BB 32
#define SS 256
#define HH 768

typedef __attribute__((ext_vector_type(8))) short bfrag8;
typedef __attribute__((ext_vector_type(4))) float accf4;

__device__ __forceinline__ unsigned short f2bf(float x) {   // RTNE fp32->bf16
    unsigned int b = __float_as_uint(x);
    return (unsigned short)((b + 0x7FFFu + ((b >> 16) & 1u)) >> 16);
}

// bf16 planes are 256 rows x 32 elems; each row = 4 fragments of 8.
// Swizzle: fragment (row, f) stored at slot f ^ ((row>>1)&3) — makes the mfma
// ds_read_b128 tile all 8 LDS bank-groups 2-way (free); measured R8: conflicts
// 3.74M -> 0.

// ---- zero the Ksum accumulator ----
__global__ __launch_bounds__(256)
void zero_kernel(float* __restrict__ Ksum) {
    Ksum[blockIdx.x * 256 + threadIdx.x] = 0.f;
}

// ---- normcvt: norms + normalized-bf16 packing + fused masked Ksum (atomics) ----
__global__ __launch_bounds__(256)
void normcvt_kernel(const float* __restrict__ Q, const float* __restrict__ K,
                    const float* __restrict__ kmask,
                    float* __restrict__ invq, float* __restrict__ invk,
                    unsigned short* __restrict__ qws, unsigned short* __restrict__ kws,
                    float* __restrict__ Ksum) {
    __shared__ float sK[4 * HH];
    const int wave = threadIdx.x >> 6, lane = threadIdx.x & 63;
    const bool isQ = blockIdx.x < 2048;          // rows 0..8191 = Q, else K
    const int rr = (blockIdx.x * 4 + wave) & 8191;
    const float4* src4 = isQ ? (const float4*)(Q + (size_t)rr * HH)
                             : (const float4*)(K + (size_t)rr * HH);
    float4 vv[3]; float s = 0.f;
#pragma unroll
    for (int c = 0; c < 3; ++c) {
        vv[c] = src4[lane + 64 * c];
        s += vv[c].x * vv[c].x + vv[c].y * vv[c].y + vv[c].z * vv[c].z + vv[c].w * vv[c].w;
    }
#pragma unroll
    for (int off = 1; off < 64; off <<= 1) s += __shfl_xor(s, off);
    float inv = 1.f / fmaxf(sqrtf(s), 1e-12f);
    if (lane == 0) (isQ ? invq : invk)[rr] = inv;

    const int b = rr >> 8, srow = rr & 255;
    unsigned short* dst = isQ ? qws : kws;
    float m = 0.f;
    if (!isQ) m = (kmask[b * SS + srow] > 0.f) ? 1.f : 0.f;
    // swizzled short-offset of this lane's 4 shorts within the 32-short row
    const int fp8 = (((((lane & 7) >> 1)) ^ ((srow >> 1) & 3)) << 3) + (lane & 1) * 4;
#pragma unroll
    for (int c = 0; c < 3; ++c) {
        int kc = (lane >> 3) + 8 * c;
        float4 n4;
        n4.x = vv[c].x * inv; n4.y = vv[c].y * inv; n4.z = vv[c].z * inv; n4.w = vv[c].w * inv;
        ushort4 o;
        o.x = f2bf(n4.x); o.y = f2bf(n4.y); o.z = f2bf(n4.z); o.w = f2bf(n4.w);
        *(ushort4*)(dst + (((size_t)b * 24 + kc) * 256 + srow) * 32 + fp8) = o;
        if (!isQ)
            *(float4*)(sK + wave * HH + (lane + 64 * c) * 4) =
                make_float4(n4.x * m, n4.y * m, n4.z * m, n4.w * m);
    }
    if (!isQ) {                                   // block-uniform branch
        __syncthreads();
        const int j = ((int)blockIdx.x - 2048) >> 6;
        for (int e = threadIdx.x; e < HH; e += 256) {
            float v = sK[e] + sK[HH + e] + sK[2 * HH + e] + sK[3 * HH + e];
            atomicAdd(&Ksum[j * HH + e], v);
        }
    }
}

// ---- main: banded QK^T + fused base (q.Ksum broadcast-B MFMA) + epilogue ----
// R9: register-prefetch pipeline. global_load_lds forced a vmcnt(0) drain at
// every barrier (LDS is shared state) — 78 us latency-bound. VGPR loads are
// thread-private: no drain at s_barrier; their wait lands at next iteration's
// ds_write, overlapped with the whole MFMA section.
__global__ __launch_bounds__(256, 3)
void mfma_kernel(const unsigned short* __restrict__ qws, const unsigned short* __restrict__ kws,
                 const float* __restrict__ qmask, const float* __restrict__ kmask,
                 const float* __restrict__ araw_p, const float* __restrict__ lscale_p,
                 const float* __restrict__ Ksum, float* __restrict__ out) {
    __shared__ short lq[8192];   // one 256x32 bf16 plane (swizzled layout)
    __shared__ short lk[8192];
    __shared__ short lKsum[768]; // bf16 Ksum[j], [kc][32]
    __shared__ float sKm[256];
    __shared__ float wtab[13];
    __shared__ float sRed[4][2];
    __shared__ float sPart[4];
    __shared__ float sKcnt, sQden;

    const int tid = threadIdx.x;
    const int lane = tid & 63, w = tid >> 6;
    const int quad = lane >> 4, col = lane & 15;
    const int i = blockIdx.x >> 5, j = blockIdx.x & 31;

    const float alpha = log1pf(__expf(araw_p[0]));
    const float scale = __expf(lscale_p[0]);

    // ---- phase A ----
    float aq = qmask[i * SS + tid];
    float km = kmask[j * SS + tid];
    sKm[tid] = km;
    float c = (km > 0.f) ? 1.f : 0.f;
#pragma unroll
    for (int off = 1; off < 64; off <<= 1) { aq += __shfl_xor(aq, off); c += __shfl_xor(c, off); }
    if (lane == 0) { sRed[w][0] = aq; sRed[w][1] = c; }
    if (tid < 13) wtab[tid] = __expf(-alpha * (float)tid);
    if (tid < 192) {              // fused ksum pack: fp32 -> bf16 into LDS
        float4 kv = ((const float4*)(Ksum + (size_t)j * HH))[tid];
        ushort4 o;
        o.x = f2bf(kv.x); o.y = f2bf(kv.y); o.z = f2bf(kv.z); o.w = f2bf(kv.w);
        ((ushort4*)lKsum)[tid] = o;
    }
    __syncthreads();
    if (tid == 0) {
        sQden = fmaxf(sRed[0][0] + sRed[1][0] + sRed[2][0] + sRed[3][0], 1.f);
        sKcnt = sRed[0][1] + sRed[1][1] + sRed[2][1] + sRed[3][1];
    }

    accf4 acc[4][3];
    accf4 accB[4];
#pragma unroll
    for (int a = 0; a < 4; ++a) {
        accB[a] = (accf4)0.f;
#pragma unroll
        for (int b = 0; b < 3; ++b) acc[a][b] = (accf4)0.f;
    }

    const size_t qb0 = (size_t)i * 24 * 8192;
    const size_t kb0 = (size_t)j * 24 * 8192;
    const int perm8 = ((quad ^ ((col >> 1) & 3)) << 3);   // swizzled fragment slot
    const unsigned short* qsrc = qws + qb0 + w * 2048 + lane * 8;
    const unsigned short* ksrc = kws + kb0 + w * 2048 + lane * 8;
    unsigned short* lqd = (unsigned short*)lq + w * 2048 + lane * 8;
    unsigned short* lkd = (unsigned short*)lk + w * 2048 + lane * 8;

    // preload chunk 0 into registers
    bfrag8 pq[4], pk[4];
#pragma unroll
    for (int n = 0; n < 4; ++n) {
        pq[n] = *(const bfrag8*)(qsrc + n * 512);
        pk[n] = *(const bfrag8*)(ksrc + n * 512);
    }

    // ---- K loop: 24 chunks of 32, software-pipelined ----
    for (int kc = 0; kc < 24; ++kc) {
        __syncthreads();                      // consumers of previous chunk done
#pragma unroll
        for (int n = 0; n < 4; ++n) {
            *(bfrag8*)(lqd + n * 512) = pq[n];
            *(bfrag8*)(lkd + n * 512) = pk[n];
        }
        {                                     // prefetch next chunk (flies over MFMA section)
            const size_t noff = (size_t)((kc < 23) ? kc + 1 : 23) * 8192;
#pragma unroll
            for (int n = 0; n < 4; ++n) {
                pq[n] = *(const bfrag8*)(qsrc + noff + n * 512);
                pk[n] = *(const bfrag8*)(ksrc + noff + n * 512);
            }
        }
        __syncthreads();                      // LDS chunk ready

        const bfrag8 kfrag = *(const bfrag8*)(lKsum + kc * 32 + quad * 8);  // broadcast
        bfrag8 bfr[6];
#pragma unroll
        for (int u = 0; u < 6; ++u) {
            int tb = 4 * w - 1 + u;
            if (tb >= 0 && tb <= 15)
                bfr[u] = *(const bfrag8*)(lk + (size_t)(tb * 16 + col) * 32 + perm8);
        }
#pragma unroll
        for (int sbl = 0; sbl < 4; ++sbl) {
            bfrag8 af = *(const bfrag8*)(lq + (size_t)((4 * w + sbl) * 16 + col) * 32 + perm8);
            accB[sbl] = __builtin_amdgcn_mfma_f32_16x16x32_bf16(af, kfrag, accB[sbl], 0, 0, 0);
#pragma unroll
            for (int dtb = 0; dtb < 3; ++dtb) {
                int tb = 4 * w + sbl - 1 + dtb;
                if (tb >= 0 && tb <= 15)
                    acc[sbl][dtb] = __builtin_amdgcn_mfma_f32_16x16x32_bf16(
                        af, bfr[sbl + dtb], acc[sbl][dtb], 0, 0, 0);
            }
        }
    }

    // ---- epilogue: C/D layout col=lane&15 (t), row=quad*4+reg (s) ----
    __syncthreads();
    const float kcnt = sKcnt;
    float part = 0.f;
#pragma unroll
    for (int sbl = 0; sbl < 4; ++sbl) {
        const int sbase = (4 * w + sbl) * 16 + quad * 4;
        float ns[4] = {0.f, 0.f, 0.f, 0.f}, ds[4] = {0.f, 0.f, 0.f, 0.f};
#pragma unroll
        for (int dtb = 0; dtb < 3; ++dtb) {
            int tb = 4 * w + sbl - 1 + dtb;
            if (tb < 0 || tb > 15) continue;
            int t = tb * 16 + col;
            float kmv = sKm[t];
#pragma unroll
            for (int reg = 0; reg < 4; ++reg) {
                int st = sbase + reg;
                int d = t - st;
                bool ok = (d >= -11) && (d <= 12) && (kmv > 0.f);
                int idx = d < 0 ? -d : d;
                idx = ok ? idx : 0;
                float raw = acc[sbl][dtb][reg];
                float e = ok ? expm1f(scale * raw * wtab[idx]) : 0.f;
                ns[reg] = fmaf(e, raw, ns[reg]);
                ds[reg] += e;
            }
        }
#pragma unroll
        for (int off = 1; off < 16; off <<= 1) {
#pragma unroll
            for (int reg = 0; reg < 4; ++reg) {
                ns[reg] += __shfl_xor(ns[reg], off);
                ds[reg] += __shfl_xor(ds[reg], off);
            }
        }
        if (col == 0) {
#pragma unroll
            for (int reg = 0; reg < 4; ++reg) {
                int st = sbase + reg;
                float qm = qmask[i * SS + st];
                float bse = accB[sbl][reg];      // fused base (all cols equal)
                float dtot = ds[reg] + kcnt;
                float v = (qm > 0.f && kcnt > 0.f) ? qm * (ns[reg] + bse) / dtot : 0.f;
                part += v;
            }
        }
    }
    part += __shfl_xor(part, 16);
    part += __shfl_xor(part, 32);
    if (lane == 0) sPart[w] = part;
    __syncthreads();
    if (tid == 0) out[i * BB + j] = (sPart[0] + sPart[1] + sPart[2] + sPart[3]) / sQden;
}

// ============ launcher ============

extern "C" void kernel_launch(void* const* d_in, const int* in_sizes, int n_in,
                              void* d_out, int out_size, void* d_ws, size_t ws_size,
                              hipStream_t stream) {
    const float* Q      = (const float*)d_in[0];
    const float* K      = (const float*)d_in[1];
    const float* qmask  = (const float*)d_in[2];
    const float* kmask  = (const float*)d_in[3];
    const float* araw   = (const float*)d_in[4];
    const float* lscale = (const float*)d_in[5];
    float* outp = (float*)d_out;

    float* invq  = (float*)d_ws;                  // 8192 f
    float* invk  = invq + 8192;                   // 8192 f
    float* Ksum  = invk + 8192;                   // 24576 f (fp32 atomic accumulator)
    unsigned short* qws = (unsigned short*)(Ksum + 24576);   // 6291456 us
    unsigned short* kws = qws + 6291456;          // 6291456 us

    zero_kernel<<<96, 256, 0, stream>>>(Ksum);
    normcvt_kernel<<<4096, 256, 0, stream>>>(Q, K, kmask, invq, invk, qws, kws, Ksum);
    mfma_kernel<<<1024, 256, 0, stream>>>(qws, kws, qmask, kmask, araw, lscale, Ksum, outp);
}